// Round 1
// baseline (2811.156 us; speedup 1.0000x reference)
//
#include <hip/hip_runtime.h>

#define VOCAB 50000
#define D 256
#define B 128
#define S 64
#define L 32
#define K 32
#define KH 16   // entity rows per recurrence block

// ---------------------------------------------------------------------------
// Extract sent_mask = prgrph_mask[:, :, 0] as int32, robust to the harness
// shipping bool as 1-byte or as int32. Probe: read first 1024 u32 words; for
// int32 layout all values are 0/1; for byte layout some word has a high byte
// set (prob of miss ~8^-1024 on random bits).
// ---------------------------------------------------------------------------
__global__ void mask_kernel(const void* mraw, int* mask_out) {
    __shared__ int flag;
    const int tid = threadIdx.x;
    if (tid == 0) flag = 0;
    __syncthreads();
    const unsigned int* w32 = (const unsigned int*)mraw;
    int loc = 0;
    for (int i = tid; i < 1024; i += 256)
        if (w32[i] > 1u) loc = 1;
    if (loc) flag = 1;   // benign race
    __syncthreads();
    const bool is_bytes = (flag != 0);
    const unsigned char* b8 = (const unsigned char*)mraw;
    const int* i32 = (const int*)mraw;
    for (int i = tid; i < B * S; i += 256)
        mask_out[i] = is_bytes ? (int)b8[(size_t)i * L] : i32[(size_t)i * L];
}

// ---------------------------------------------------------------------------
// enc_sents[b,s,:] = sum_l E[prgrph[b,s,l], :]
// ---------------------------------------------------------------------------
__global__ void embed_kernel(const int* __restrict__ prgrph,
                             const float* __restrict__ E,
                             float* __restrict__ enc) {
    const int bs = blockIdx.x;
    const int c  = threadIdx.x;
    __shared__ int sidx[L];
    if (c < L) sidx[c] = prgrph[bs * L + c];
    __syncthreads();
    float acc = 0.f;
    #pragma unroll
    for (int l = 0; l < L; ++l)
        acc += E[(size_t)sidx[l] * D + c];
    enc[(size_t)bs * D + c] = acc;
}

// ---------------------------------------------------------------------------
// O[r,:] = A[r,:] @ Bm  for 32 rows per block. A-tile in LDS (broadcast
// reads), Bm streamed column-coalesced from L2.
// ---------------------------------------------------------------------------
__global__ void gemm_kernel(const float* __restrict__ A,
                            const float* __restrict__ Bm,
                            float* __restrict__ O) {
    const int row0 = blockIdx.x * 32;
    const int c = threadIdx.x;
    __shared__ float a_s[32 * D];
    for (int i = c; i < 32 * D; i += 256)
        a_s[i] = A[(size_t)row0 * D + i];
    __syncthreads();
    float acc[32];
    #pragma unroll
    for (int r = 0; r < 32; ++r) acc[r] = 0.f;
    #pragma unroll 8
    for (int d = 0; d < D; ++d) {
        const float w = Bm[d * D + c];
        #pragma unroll
        for (int r = 0; r < 32; ++r) acc[r] += a_s[r * D + d] * w;
    }
    #pragma unroll
    for (int r = 0; r < 32; ++r)
        O[(size_t)(row0 + r) * D + c] = acc[r];
}

// ---------------------------------------------------------------------------
// The recurrence. One block per (b, K-half). h (KH x D) lives in LDS for all
// 64 steps. Steps with mask==0 are skipped entirely (h_new == h).
// ---------------------------------------------------------------------------
__device__ __forceinline__ float wave_red(float v) {
    #pragma unroll
    for (int o = 32; o > 0; o >>= 1) v += __shfl_xor(v, o);
    return v;
}

__global__ __launch_bounds__(256) void recur_kernel(
    const float* __restrict__ enc, const float* __restrict__ eWp,
    const float* __restrict__ keysV, const float* __restrict__ keys,
    const float* __restrict__ U, const int* __restrict__ mask,
    float* __restrict__ out) {
    const int b  = blockIdx.x >> 1;
    const int kh = (blockIdx.x & 1) * KH;
    const int c  = threadIdx.x;

    __shared__ float h_s[KH * D];        // 16 KB
    __shared__ float red[KH * 4];
    __shared__ float gate_s[KH];
    __shared__ float rn_s[KH];

    float keys_r[KH], keysV_r[KH];
    #pragma unroll
    for (int r = 0; r < KH; ++r) {
        const size_t row = (size_t)(b * K + kh + r);
        keys_r[r]  = keys[row * D + c];
        keysV_r[r] = keysV[row * D + c];
        h_s[r * D + c] = 0.f;
    }
    __syncthreads();

    const int wave = c >> 6, lane = c & 63;
    const int* bm = mask + b * S;

    for (int s = 0; s < S; ++s) {
        if (!bm[s]) continue;  // uniform per block: h unchanged this step

        const size_t esoff = ((size_t)b * S + s) * D + c;
        const float e_c  = enc[esoff];
        const float eW_c = eWp[esoff];

        // ---- gate[r] = sigmoid( sum_d e[d] * (h[r,d] + keys[r,d]) ) ----
        float p[KH];
        #pragma unroll
        for (int r = 0; r < KH; ++r)
            p[r] = e_c * (h_s[r * D + c] + keys_r[r]);
        #pragma unroll
        for (int r = 0; r < KH; ++r) {
            const float v = wave_red(p[r]);
            if (lane == 0) red[r * 4 + wave] = v;
        }
        __syncthreads();
        if (c < KH) {
            const float g = red[c * 4 + 0] + red[c * 4 + 1] +
                            red[c * 4 + 2] + red[c * 4 + 3];
            gate_s[c] = 1.f / (1.f + __expf(-g));
        }
        __syncthreads();

        // ---- acc[r] = (h @ U)[r, c] ----
        float acc[KH];
        #pragma unroll
        for (int r = 0; r < KH; ++r) acc[r] = 0.f;
        #pragma unroll 8
        for (int d = 0; d < D; ++d) {
            const float u = U[d * D + c];
            #pragma unroll
            for (int r = 0; r < KH; ++r) acc[r] += h_s[r * D + d] * u;
        }

        // ---- upd + row L2 norm ----
        float up[KH];
        #pragma unroll
        for (int r = 0; r < KH; ++r) {
            float ht = acc[r] + keysV_r[r] + eW_c;
            ht = fmaxf(ht, 0.f);
            up[r] = h_s[r * D + c] + gate_s[r] * ht;
            p[r] = up[r] * up[r];
        }
        #pragma unroll
        for (int r = 0; r < KH; ++r) {
            const float v = wave_red(p[r]);
            if (lane == 0) red[r * 4 + wave] = v;
        }
        __syncthreads();   // also guarantees all h_s reads above are done
        if (c < KH) {
            const float ss = red[c * 4 + 0] + red[c * 4 + 1] +
                             red[c * 4 + 2] + red[c * 4 + 3];
            rn_s[c] = rsqrtf(fmaxf(ss, 1e-12f));
        }
        __syncthreads();
        #pragma unroll
        for (int r = 0; r < KH; ++r)
            h_s[r * D + c] = up[r] * rn_s[r];
        __syncthreads();
    }

    #pragma unroll
    for (int r = 0; r < KH; ++r)
        out[((size_t)(b * K + kh + r)) * D + c] = h_s[r * D + c];
}

extern "C" void kernel_launch(void* const* d_in, const int* in_sizes, int n_in,
                              void* d_out, int out_size, void* d_ws, size_t ws_size,
                              hipStream_t stream) {
    const int*   prgrph = (const int*)d_in[0];
    const void*  pmask  = d_in[1];                // bool: layout probed on device
    const float* keys   = (const float*)d_in[2];
    const float* E      = (const float*)d_in[3];
    const float* U      = (const float*)d_in[4];
    const float* V      = (const float*)d_in[5];
    const float* W      = (const float*)d_in[6];
    float* out = (float*)d_out;

    // workspace layout (floats)
    float* ws_enc   = (float*)d_ws;                        // B*S*D
    float* ws_eW    = ws_enc + (size_t)B * S * D;          // B*S*D
    float* ws_keysV = ws_eW  + (size_t)B * S * D;          // B*K*D
    int*   ws_mask  = (int*)(ws_keysV + (size_t)B * K * D); // B*S

    mask_kernel<<<1, 256, 0, stream>>>(pmask, ws_mask);
    embed_kernel<<<B * S, 256, 0, stream>>>(prgrph, E, ws_enc);
    gemm_kernel<<<(B * S) / 32, 256, 0, stream>>>(ws_enc, W, ws_eW);
    gemm_kernel<<<(B * K) / 32, 256, 0, stream>>>(keys, V, ws_keysV);
    recur_kernel<<<B * (K / KH), 256, 0, stream>>>(
        ws_enc, ws_eW, ws_keysV, keys, U, ws_mask, out);
}

// Round 2
// 351.508 us; speedup vs baseline: 7.9974x; 7.9974x over previous
//
#include <hip/hip_runtime.h>

#define D 256
#define B 128
#define S 64
#define L 32
#define K 32
#define KH 16
#define HSTR 260   // padded row stride (u32 words) for hM: 260%32=4 -> 2-way banks (free)

typedef short bf16x8 __attribute__((ext_vector_type(8)));  // 8 bf16 in 4 VGPRs (guide-verified form)
typedef float f32x4 __attribute__((ext_vector_type(4)));

__device__ __forceinline__ unsigned short f2bf(float f) {   // RNE float->bf16 bits
    unsigned u = __float_as_uint(f);
    u += 0x7fffu + ((u >> 16) & 1u);
    return (unsigned short)(u >> 16);
}
__device__ __forceinline__ float bf2f(unsigned short h) {
    return __uint_as_float(((unsigned)h) << 16);
}

// ---------------------------------------------------------------------------
// sent_mask extraction, robust to bool shipped as 1-byte or int32.
// ---------------------------------------------------------------------------
__global__ void mask_kernel(const void* mraw, int* mask_out) {
    __shared__ int flag;
    const int tid = threadIdx.x;
    if (tid == 0) flag = 0;
    __syncthreads();
    const unsigned int* w32 = (const unsigned int*)mraw;
    int loc = 0;
    for (int i = tid; i < 1024; i += 256)
        if (w32[i] > 1u) loc = 1;
    if (loc) flag = 1;   // benign race
    __syncthreads();
    const bool is_bytes = (flag != 0);
    const unsigned char* b8 = (const unsigned char*)mraw;
    const int* i32 = (const int*)mraw;
    for (int i = tid; i < B * S; i += 256)
        mask_out[i] = is_bytes ? (int)b8[(size_t)i * L] : i32[(size_t)i * L];
}

// ---------------------------------------------------------------------------
// enc_sents[b,s,:] = sum_l E[prgrph[b,s,l], :]
// ---------------------------------------------------------------------------
__global__ void embed_kernel(const int* __restrict__ prgrph,
                             const float* __restrict__ E,
                             float* __restrict__ enc) {
    const int bs = blockIdx.x;
    const int c  = threadIdx.x;
    __shared__ int sidx[L];
    if (c < L) sidx[c] = prgrph[bs * L + c];
    __syncthreads();
    float acc = 0.f;
    #pragma unroll
    for (int l = 0; l < L; ++l)
        acc += E[(size_t)sidx[l] * D + c];
    enc[(size_t)bs * D + c] = acc;
}

// ---------------------------------------------------------------------------
// O[r,:] = A[r,:] @ Bm, 32 rows/block. Register-tiled: wave -> 8 rows, thread
// -> 8 rows x 4 cols. LDS b128 broadcasts + float4 global loads.
// ---------------------------------------------------------------------------
__global__ __launch_bounds__(256) void gemm_kernel(const float* __restrict__ A,
                                                   const float* __restrict__ Bm,
                                                   float* __restrict__ O) {
    const int row0 = blockIdx.x * 32;
    const int t = threadIdx.x, wave = t >> 6, lane = t & 63;
    __shared__ float a_s[32 * D];
    const float4* Ag = (const float4*)(A + (size_t)row0 * D);
    float4* As4 = (float4*)a_s;
    for (int i = t; i < 32 * D / 4; i += 256) As4[i] = Ag[i];
    __syncthreads();
    const int r0 = wave * 8;
    const int c0 = lane * 4;
    float4 acc[8];
    #pragma unroll
    for (int i = 0; i < 8; ++i) acc[i] = make_float4(0.f, 0.f, 0.f, 0.f);
    for (int d = 0; d < D; d += 4) {
        float4 av[8];
        #pragma unroll
        for (int i = 0; i < 8; ++i) av[i] = *(const float4*)&a_s[(r0 + i) * D + d];
        #pragma unroll
        for (int j = 0; j < 4; ++j) {
            const float4 w = *(const float4*)(Bm + (size_t)(d + j) * D + c0);
            #pragma unroll
            for (int i = 0; i < 8; ++i) {
                const float a = (j == 0) ? av[i].x : (j == 1) ? av[i].y
                              : (j == 2) ? av[i].z : av[i].w;
                acc[i].x += a * w.x; acc[i].y += a * w.y;
                acc[i].z += a * w.z; acc[i].w += a * w.w;
            }
        }
    }
    #pragma unroll
    for (int i = 0; i < 8; ++i)
        *(float4*)&O[(size_t)(row0 + r0 + i) * D + c0] = acc[i];
}

// ---------------------------------------------------------------------------
// Recurrence, MFMA version. Block = (b, 16-row half of K). 4 waves; wave w
// owns output cols [64w, 64w+64). Lane (n=lane&15, quad=lane>>4):
//   C/D layout: row = quad*4+reg, col = 64w + 16*sub + n  (16 fp32 per lane)
//   A-frag:     A[m=lane&15][k = 32*kt + 8*quad + j]
//   B-frag:     B[k = 32*kt + 8*quad + j][ncol = lane&15]  (U, preloaded regs)
// h kept UNNORMALIZED in regs (upv) + LDS image hM (packed bf16 hi|lo);
// rn (row inv-norm) folded into MFMA output rows -> only 2 barriers/step.
// ---------------------------------------------------------------------------
__global__ __launch_bounds__(256, 1) void recur_kernel(
    const float* __restrict__ enc, const float* __restrict__ eWp,
    const float* __restrict__ keysV, const float* __restrict__ keys,
    const float* __restrict__ U, const int* __restrict__ mask,
    float* __restrict__ out) {
    const int b  = blockIdx.x >> 1;
    const int kh = (blockIdx.x & 1) * KH;
    const int t = threadIdx.x;
    const int wave = t >> 6, lane = t & 63;
    const int n = lane & 15, quad = lane >> 4;

    __shared__ unsigned hM[KH * HSTR];     // packed: low16=bf16(hi), high16=bf16(lo)
    __shared__ float redG[KH][4];
    __shared__ float redN[KH][4];

    for (int i = t; i < KH * HSTR; i += 256) hM[i] = 0u;

    // ---- preload U B-fragments (hi/lo), step-invariant -> registers ----
    bf16x8 Uhi[4][8], Ulo[4][8];
    #pragma unroll
    for (int sub = 0; sub < 4; ++sub) {
        const int col = wave * 64 + sub * 16 + n;
        #pragma unroll
        for (int kt = 0; kt < 8; ++kt) {
            #pragma unroll
            for (int j = 0; j < 8; ++j) {
                const int k = kt * 32 + quad * 8 + j;
                const float u = U[(size_t)k * D + col];
                const unsigned short h16 = f2bf(u);
                Uhi[sub][kt][j] = (short)h16;
                Ulo[sub][kt][j] = (short)f2bf(u - bf2f(h16));
            }
        }
    }

    // ---- per-lane C-layout state ----
    float upv[4][4];            // unnormalized h rows; actual h = rn[reg]*upv
    float rn[4];
    float keys_c[4][4], keysV_c[4][4];
    #pragma unroll
    for (int reg = 0; reg < 4; ++reg) {
        rn[reg] = 1.f;
        const int row = quad * 4 + reg;
        const size_t base = (size_t)(b * K + kh + row) * D;
        #pragma unroll
        for (int sub = 0; sub < 4; ++sub) {
            const int col = wave * 64 + sub * 16 + n;
            upv[reg][sub]   = 0.f;
            keys_c[reg][sub]  = keys[base + col];
            keysV_c[reg][sub] = keysV[base + col];
        }
    }
    __syncthreads();

    const int* bm = mask + b * S;
    for (int s = 0; s < S; ++s) {
        if (!bm[s]) continue;              // uniform per block: h unchanged

        const size_t eo = (size_t)(b * S + s) * D;
        float e_c[4], eW_c[4];
        #pragma unroll
        for (int sub = 0; sub < 4; ++sub) {
            const int col = wave * 64 + sub * 16 + n;
            e_c[sub]  = enc[eo + col];
            eW_c[sub] = eWp[eo + col];
        }

        // ---- acc = upv_prev @ U (3-term split: hi*Uhi + lo*Uhi + hi*Ulo) ----
        f32x4 acc[4] = {{0.f,0.f,0.f,0.f},{0.f,0.f,0.f,0.f},
                        {0.f,0.f,0.f,0.f},{0.f,0.f,0.f,0.f}};
        const unsigned* hrow = &hM[n * HSTR];   // A-frag m = lane&15 = n
        #pragma unroll
        for (int kt = 0; kt < 8; ++kt) {
            const unsigned* p = hrow + kt * 32 + quad * 8;
            const uint4 w0 = *(const uint4*)p;
            const uint4 w1 = *(const uint4*)(p + 4);
            bf16x8 ahi, alo;
            ahi[0] = (short)(w0.x & 0xffffu); alo[0] = (short)(w0.x >> 16);
            ahi[1] = (short)(w0.y & 0xffffu); alo[1] = (short)(w0.y >> 16);
            ahi[2] = (short)(w0.z & 0xffffu); alo[2] = (short)(w0.z >> 16);
            ahi[3] = (short)(w0.w & 0xffffu); alo[3] = (short)(w0.w >> 16);
            ahi[4] = (short)(w1.x & 0xffffu); alo[4] = (short)(w1.x >> 16);
            ahi[5] = (short)(w1.y & 0xffffu); alo[5] = (short)(w1.y >> 16);
            ahi[6] = (short)(w1.z & 0xffffu); alo[6] = (short)(w1.z >> 16);
            ahi[7] = (short)(w1.w & 0xffffu); alo[7] = (short)(w1.w >> 16);
            #pragma unroll
            for (int sub = 0; sub < 4; ++sub) {
                acc[sub] = __builtin_amdgcn_mfma_f32_16x16x32_bf16(ahi, Uhi[sub][kt], acc[sub], 0, 0, 0);
                acc[sub] = __builtin_amdgcn_mfma_f32_16x16x32_bf16(alo, Uhi[sub][kt], acc[sub], 0, 0, 0);
                acc[sub] = __builtin_amdgcn_mfma_f32_16x16x32_bf16(ahi, Ulo[sub][kt], acc[sub], 0, 0, 0);
            }
        }

        // ---- gate partial: pc[reg] = sum_cols e * (rn*upv + keys) ----
        float pc[4];
        #pragma unroll
        for (int reg = 0; reg < 4; ++reg) {
            float v = 0.f;
            #pragma unroll
            for (int sub = 0; sub < 4; ++sub)
                v += e_c[sub] * (rn[reg] * upv[reg][sub] + keys_c[reg][sub]);
            pc[reg] = v;
        }
        #pragma unroll
        for (int m = 1; m <= 8; m <<= 1) {
            #pragma unroll
            for (int reg = 0; reg < 4; ++reg) pc[reg] += __shfl_xor(pc[reg], m);
        }
        if (n == 0) {
            #pragma unroll
            for (int reg = 0; reg < 4; ++reg) redG[quad * 4 + reg][wave] = pc[reg];
        }
        __syncthreads();                    // barrier 1 (also: A-reads < h-writes)

        float gate[4];
        #pragma unroll
        for (int reg = 0; reg < 4; ++reg) {
            const float4 g4 = *(const float4*)redG[quad * 4 + reg];
            const float g = g4.x + g4.y + g4.z + g4.w;
            gate[reg] = 1.f / (1.f + __expf(-g));
        }

        // ---- up_new = rn*upv + gate*relu(rn*acc + keysV + eW); write hM ----
        float pn[4];
        #pragma unroll
        for (int reg = 0; reg < 4; ++reg) {
            const int row = quad * 4 + reg;
            float sq = 0.f;
            #pragma unroll
            for (int sub = 0; sub < 4; ++sub) {
                float ht = rn[reg] * acc[sub][reg] + keysV_c[reg][sub] + eW_c[sub];
                ht = fmaxf(ht, 0.f);
                const float u2 = rn[reg] * upv[reg][sub] + gate[reg] * ht;
                upv[reg][sub] = u2;
                sq += u2 * u2;
                const unsigned short hi = f2bf(u2);
                const unsigned short lo = f2bf(u2 - bf2f(hi));
                hM[row * HSTR + wave * 64 + sub * 16 + n] =
                    (unsigned)hi | ((unsigned)lo << 16);
            }
            pn[reg] = sq;
        }
        #pragma unroll
        for (int m = 1; m <= 8; m <<= 1) {
            #pragma unroll
            for (int reg = 0; reg < 4; ++reg) pn[reg] += __shfl_xor(pn[reg], m);
        }
        if (n == 0) {
            #pragma unroll
            for (int reg = 0; reg < 4; ++reg) redN[quad * 4 + reg][wave] = pn[reg];
        }
        __syncthreads();                    // barrier 2 (protects hM for next step)

        #pragma unroll
        for (int reg = 0; reg < 4; ++reg) {
            const float4 r4 = *(const float4*)redN[quad * 4 + reg];
            const float ss = r4.x + r4.y + r4.z + r4.w;
            rn[reg] = rsqrtf(fmaxf(ss, 1e-12f));
        }
    }

    #pragma unroll
    for (int reg = 0; reg < 4; ++reg) {
        const int row = quad * 4 + reg;
        const size_t base = (size_t)(b * K + kh + row) * D;
        #pragma unroll
        for (int sub = 0; sub < 4; ++sub)
            out[base + wave * 64 + sub * 16 + n] = rn[reg] * upv[reg][sub];
    }
}

extern "C" void kernel_launch(void* const* d_in, const int* in_sizes, int n_in,
                              void* d_out, int out_size, void* d_ws, size_t ws_size,
                              hipStream_t stream) {
    const int*   prgrph = (const int*)d_in[0];
    const void*  pmask  = d_in[1];
    const float* keys   = (const float*)d_in[2];
    const float* E      = (const float*)d_in[3];
    const float* U      = (const float*)d_in[4];
    const float* V      = (const float*)d_in[5];
    const float* W      = (const float*)d_in[6];
    float* out = (float*)d_out;

    float* ws_enc   = (float*)d_ws;                         // B*S*D
    float* ws_eW    = ws_enc + (size_t)B * S * D;           // B*S*D
    float* ws_keysV = ws_eW  + (size_t)B * S * D;           // B*K*D
    int*   ws_mask  = (int*)(ws_keysV + (size_t)B * K * D); // B*S

    mask_kernel<<<1, 256, 0, stream>>>(pmask, ws_mask);
    embed_kernel<<<B * S, 256, 0, stream>>>(prgrph, E, ws_enc);
    gemm_kernel<<<(B * S) / 32, 256, 0, stream>>>(ws_enc, W, ws_eW);
    gemm_kernel<<<(B * K) / 32, 256, 0, stream>>>(keys, V, ws_keysV);
    recur_kernel<<<B * (K / KH), 256, 0, stream>>>(
        ws_enc, ws_eW, ws_keysV, keys, U, ws_mask, out);
}